// Round 14
// baseline (116.473 us; speedup 1.0000x reference)
//
#include <hip/hip_runtime.h>
#include <math.h>

#define TYPE_N 5
#define D 256
#define EPS 1e-6f
#define NCOPY 16
#define RPB 128   // rows per block in k1 (block-uniform label scheme)

// ws layout (float offsets):
//   [0, 20480)        sums_partial[NCOPY][TYPE_N][D]
//   [20480, 20560)    counts_partial[NCOPY][TYPE_N]
//   [20560, 21840)    center[TYPE_N][D]          (raw)
//   [21840, 21845)    counts_final[TYPE_N]
//   [21845, 21925)    dsum_partial[NCOPY][TYPE_N]
//   [21925, 23205)    cme[TYPE_N][D]             (center - EPS)
#define OFF_CNTP   (NCOPY * TYPE_N * D)          // 20480
#define OFF_CENTER (OFF_CNTP + NCOPY * TYPE_N)   // 20560
#define OFF_CNTF   (OFF_CENTER + TYPE_N * D)     // 21840
#define OFF_DSUM   (OFF_CNTF + TYPE_N)           // 21845
#define OFF_CME    (OFF_DSUM + NCOPY * TYPE_N)   // 21925
#define WS_FLOATS  (OFF_CME + TYPE_N * D)        // 23205

__device__ __forceinline__ int argmax5(const float* __restrict__ yr) {
    int lab = 0;
    float best = yr[0];
    #pragma unroll
    for (int c = 1; c < TYPE_N; ++c) {
        float v = yr[c];
        if (v > best) { best = v; lab = c; }
    }
    return lab;
}

// --- K1: counts + centroid column sums ---------------------------------------
// k1n structure (A/B-proven R10/R11) with ONE minimal delta: 8 rows per
// iteration -> each wave issues TWO independent float4 row-loads back-to-back
// (rows rb+2*sub, rb+2*sub+1), doubling loads in flight (k3's unroll lesson).
// Labels remain BLOCK-UNIFORM (scalarized, off the per-lane critical path).
__global__ __launch_bounds__(256) void k1_sums(const float* __restrict__ x,
                                               const float* __restrict__ y,
                                               float* __restrict__ ws, int N) {
    __shared__ float lsum[4][TYPE_N][D];
    __shared__ float lcnt[4][TYPE_N];
    const int lane = threadIdx.x & 63;
    const int sub  = threadIdx.x >> 6;
    const int r0   = blockIdx.x * RPB;
    const int rows = (N - r0 < RPB) ? (N - r0) : RPB;

    float acc[TYPE_N][4] = {};
    float cnt[TYPE_N] = {};
    const float cw = (lane == 0) ? 1.0f : 0.0f;  // lane0 of each wave counts its rows

    const int ng = rows >> 3;   // 8 rows per iteration
    for (int i = 0; i < ng; ++i) {
        const int rb = r0 + i * 8;
        // 8 block-uniform labels (scalar loads, hoisted off the VMEM path)
        const int lab0 = argmax5(y + (size_t)(rb + 0) * TYPE_N);
        const int lab1 = argmax5(y + (size_t)(rb + 1) * TYPE_N);
        const int lab2 = argmax5(y + (size_t)(rb + 2) * TYPE_N);
        const int lab3 = argmax5(y + (size_t)(rb + 3) * TYPE_N);
        const int lab4 = argmax5(y + (size_t)(rb + 4) * TYPE_N);
        const int lab5 = argmax5(y + (size_t)(rb + 5) * TYPE_N);
        const int lab6 = argmax5(y + (size_t)(rb + 6) * TYPE_N);
        const int lab7 = argmax5(y + (size_t)(rb + 7) * TYPE_N);
        int labA = lab0, labB = lab1;
        labA = (sub == 1) ? lab2 : labA;  labB = (sub == 1) ? lab3 : labB;
        labA = (sub == 2) ? lab4 : labA;  labB = (sub == 2) ? lab5 : labB;
        labA = (sub == 3) ? lab6 : labA;  labB = (sub == 3) ? lab7 : labB;
        // two independent coalesced row-loads per wave (2x in flight)
        const float4 v0 = *reinterpret_cast<const float4*>(
            x + (size_t)(rb + 2 * sub) * D + lane * 4);
        const float4 v1 = *reinterpret_cast<const float4*>(
            x + (size_t)(rb + 2 * sub + 1) * D + lane * 4);
        #pragma unroll
        for (int c = 0; c < TYPE_N; ++c) {
            const float mA = (labA == c) ? 1.0f : 0.0f;
            acc[c][0] = fmaf(mA, v0.x, acc[c][0]);
            acc[c][1] = fmaf(mA, v0.y, acc[c][1]);
            acc[c][2] = fmaf(mA, v0.z, acc[c][2]);
            acc[c][3] = fmaf(mA, v0.w, acc[c][3]);
            cnt[c]    = fmaf(mA, cw, cnt[c]);
        }
        #pragma unroll
        for (int c = 0; c < TYPE_N; ++c) {
            const float mB = (labB == c) ? 1.0f : 0.0f;
            acc[c][0] = fmaf(mB, v1.x, acc[c][0]);
            acc[c][1] = fmaf(mB, v1.y, acc[c][1]);
            acc[c][2] = fmaf(mB, v1.z, acc[c][2]);
            acc[c][3] = fmaf(mB, v1.w, acc[c][3]);
            cnt[c]    = fmaf(mB, cw, cnt[c]);
        }
    }
    for (int r = r0 + (ng << 3) + sub; r < r0 + rows; r += 4) {  // tail rows (<8)
        const int lab = argmax5(y + (size_t)r * TYPE_N);
        const float4 v = *reinterpret_cast<const float4*>(
            x + (size_t)r * D + lane * 4);
        #pragma unroll
        for (int c = 0; c < TYPE_N; ++c) {
            const float m = (lab == c) ? 1.0f : 0.0f;
            acc[c][0] = fmaf(m, v.x, acc[c][0]);
            acc[c][1] = fmaf(m, v.y, acc[c][1]);
            acc[c][2] = fmaf(m, v.z, acc[c][2]);
            acc[c][3] = fmaf(m, v.w, acc[c][3]);
            cnt[c]    = fmaf(m, cw, cnt[c]);
        }
    }

    #pragma unroll
    for (int c = 0; c < TYPE_N; ++c) {
        *reinterpret_cast<float4*>(&lsum[sub][c][lane * 4]) =
            make_float4(acc[c][0], acc[c][1], acc[c][2], acc[c][3]);
        if (lane == 0) lcnt[sub][c] = cnt[c];
    }
    __syncthreads();
    const int t = threadIdx.x;
    float* sums = ws + (size_t)(blockIdx.x % NCOPY) * (TYPE_N * D);
    #pragma unroll
    for (int c = 0; c < TYPE_N; ++c) {
        float s = lsum[0][c][t] + lsum[1][c][t] + lsum[2][c][t] + lsum[3][c][t];
        atomicAdd(&sums[c * D + t], s);
    }
    if (t < TYPE_N) {
        float s = lcnt[0][t] + lcnt[1][t] + lcnt[2][t] + lcnt[3][t];
        atomicAdd(&ws[OFF_CNTP + (blockIdx.x % NCOPY) * TYPE_N + t], s);
    }
}

// --- K2: reduce copies -> centers (raw + eps-folded) ------------------------
__global__ __launch_bounds__(256) void k2_center(float* __restrict__ ws) {
    const int t = threadIdx.x;  // column 0..255
    float cnts[TYPE_N];
    #pragma unroll
    for (int c = 0; c < TYPE_N; ++c) {
        float s = 0.f;
        #pragma unroll
        for (int p = 0; p < NCOPY; ++p) s += ws[OFF_CNTP + p * TYPE_N + c];
        cnts[c] = s;
    }
    float* center = ws + OFF_CENTER;
    float* cme    = ws + OFF_CME;
    #pragma unroll
    for (int c = 0; c < TYPE_N; ++c) {
        float s = 0.f;
        #pragma unroll
        for (int p = 0; p < NCOPY; ++p) s += ws[p * TYPE_N * D + c * D + t];
        float sc = fmaxf(cnts[c], 1.0f);
        float ctr = (cnts[c] > 0.f) ? s / sc : 0.f;
        center[c * D + t] = ctr;
        cme[c * D + t]    = ctr - EPS;
    }
    if (t < TYPE_N) ws[OFF_CNTF + t] = cnts[t];
}

// --- K3: row-per-thread distances (R11-exact, forward order) ----------------
__global__ __launch_bounds__(256) void k3_dist(const float* __restrict__ x,
                                               const float* __restrict__ y,
                                               float* __restrict__ ws, int N) {
    __shared__ float lds[4][TYPE_N];
    const int lane = threadIdx.x & 63;
    const int wid  = threadIdx.x >> 6;
    const int r = blockIdx.x * 256 + threadIdx.x;

    int lab = 0;
    float d = 0.f;
    if (r < N) {
        lab = argmax5(y + (size_t)r * TYPE_N);
        const float4* xr = reinterpret_cast<const float4*>(x + (size_t)r * D);
        const float4* cr = reinterpret_cast<const float4*>(ws + OFF_CME + lab * D);
        float ss[4] = {0.f, 0.f, 0.f, 0.f};
        #pragma unroll 8
        for (int i = 0; i < 64; ++i) {
            const float4 a = xr[i];
            const float4 b = cr[i];
            const float t0 = a.x - b.x;
            const float t1 = a.y - b.y;
            const float t2 = a.z - b.z;
            const float t3 = a.w - b.w;
            float s = fmaf(t0, t0, t1 * t1);
            s = fmaf(t2, t2, s);
            s = fmaf(t3, t3, s);
            ss[i & 3] += s;
        }
        d = sqrtf(ss[0] + ss[1] + ss[2] + ss[3]);
    }

    #pragma unroll
    for (int c = 0; c < TYPE_N; ++c) {
        float v = (lab == c) ? d : 0.f;
        #pragma unroll
        for (int off = 32; off > 0; off >>= 1) v += __shfl_xor(v, off);
        if (lane == 0) lds[wid][c] = v;
    }
    __syncthreads();
    if (threadIdx.x < TYPE_N) {
        float s = lds[0][threadIdx.x] + lds[1][threadIdx.x] +
                  lds[2][threadIdx.x] + lds[3][threadIdx.x];
        atomicAdd(&ws[OFF_DSUM + (blockIdx.x % NCOPY) * TYPE_N + threadIdx.x], s);
    }
}

// --- K4: scalar epilogue -----------------------------------------------------
__global__ __launch_bounds__(64) void k4_final(const float* __restrict__ ws,
                                               float* __restrict__ out) {
    const int lane = threadIdx.x;  // 0..63
    const float* center = ws + OFF_CENTER;
    const float* counts = ws + OFF_CNTF;
    const float* dsp    = ws + OFF_DSUM;

    float csum[TYPE_N];
    #pragma unroll
    for (int c = 0; c < TYPE_N; ++c) {
        float s = 0.f;
        #pragma unroll
        for (int k = 0; k < 4; ++k) s += center[c * D + lane * 4 + k];
        #pragma unroll
        for (int off = 32; off > 0; off >>= 1) s += __shfl_xor(s, off);
        csum[c] = s;
    }

    float cnts[TYPE_N], dsum[TYPE_N];
    bool present[TYPE_N];
    float real_n = 0.f;
    #pragma unroll
    for (int c = 0; c < TYPE_N; ++c) {
        cnts[c] = counts[c];
        float s = 0.f;
        #pragma unroll
        for (int p = 0; p < NCOPY; ++p) s += dsp[p * TYPE_N + c];
        dsum[c] = s;
        present[c] = (cnts[c] > 0.f) && (csum[c] != 0.f);
        real_n += present[c] ? 1.f : 0.f;
    }

    float loss_pos = 0.f;
    #pragma unroll
    for (int c = 0; c < TYPE_N; ++c) {
        float pcm = dsum[c] / fmaxf(cnts[c], 1.f);
        loss_pos += present[c] ? pcm : 0.f;
    }
    loss_pos = (real_n > 0.f) ? loss_pos / fmaxf(real_n, 1.f) : 1.0f;

    float pairsum = 0.f;
    #pragma unroll
    for (int i = 0; i < TYPE_N; ++i) {
        #pragma unroll
        for (int j = i + 1; j < TYPE_N; ++j) {
            float s = 0.f;
            #pragma unroll
            for (int k = 0; k < 4; ++k) {
                float dd = center[i * D + lane * 4 + k] - center[j * D + lane * 4 + k] + EPS;
                s += dd * dd;
            }
            #pragma unroll
            for (int off = 32; off > 0; off >>= 1) s += __shfl_xor(s, off);
            float pd = sqrtf(s);
            pairsum += (present[i] && present[j]) ? pd : 0.f;
        }
    }
    float n_pairs = real_n * (real_n - 1.f) * 0.5f;
    float loss_neg = (real_n > 1.f) ? pairsum / fmaxf(n_pairs, 1.f) : 0.f;

    if (lane == 0) out[0] = loss_pos / (loss_neg + loss_pos);
}

extern "C" void kernel_launch(void* const* d_in, const int* in_sizes, int n_in,
                              void* d_out, int out_size, void* d_ws, size_t ws_size,
                              hipStream_t stream) {
    const float* x = (const float*)d_in[0];
    const float* y = (const float*)d_in[1];
    float* out = (float*)d_out;
    float* ws  = (float*)d_ws;
    const int N = in_sizes[0] / D;  // 200000

    (void)hipMemsetAsync(d_ws, 0, (size_t)WS_FLOATS * sizeof(float), stream);

    const int grid1 = (N + RPB - 1) / RPB;   // 1563 blocks, 128 rows each
    k1_sums<<<grid1, 256, 0, stream>>>(x, y, ws, N);
    k2_center<<<1, 256, 0, stream>>>(ws);
    const int grid3 = (N + 255) / 256;       // one row per thread
    k3_dist<<<grid3, 256, 0, stream>>>(x, y, ws, N);
    k4_final<<<1, 64, 0, stream>>>(ws, out);
}

// Round 15
// 109.353 us; speedup vs baseline: 1.0651x; 1.0651x over previous
//
#include <hip/hip_runtime.h>
#include <math.h>

#define TYPE_N 5
#define D 256
#define EPS 1e-6f
#define NCOPY 16
#define RPB 128   // rows per block in k1; wave owns a contiguous 32-row sub-slab

// ws layout (float offsets):
//   [0, 20480)        sums_partial[NCOPY][TYPE_N][D]
//   [20480, 20560)    counts_partial[NCOPY][TYPE_N]
//   [20560, 21840)    center[TYPE_N][D]          (raw)
//   [21840, 21845)    counts_final[TYPE_N]
//   [21845, 21925)    dsum_partial[NCOPY][TYPE_N]
//   [21925, 23205)    cme[TYPE_N][D]             (center - EPS)
#define OFF_CNTP   (NCOPY * TYPE_N * D)          // 20480
#define OFF_CENTER (OFF_CNTP + NCOPY * TYPE_N)   // 20560
#define OFF_CNTF   (OFF_CENTER + TYPE_N * D)     // 21840
#define OFF_DSUM   (OFF_CNTF + TYPE_N)           // 21845
#define OFF_CME    (OFF_DSUM + NCOPY * TYPE_N)   // 21925
#define WS_FLOATS  (OFF_CME + TYPE_N * D)        // 23205

__device__ __forceinline__ int argmax5(const float* __restrict__ yr) {
    int lab = 0;
    float best = yr[0];
    #pragma unroll
    for (int c = 1; c < TYPE_N; ++c) {
        float v = yr[c];
        if (v > best) { best = v; lab = c; }
    }
    return lab;
}

// --- K1: counts + centroid column sums ---------------------------------------
// k1n block-slab structure with ONE delta vs R13: wave `sub` walks a
// CONTIGUOUS 32-row sub-slab sequentially, 4 rows/iter (4KB of consecutive
// addresses in flight — k3's proven sequential-burst engine at wave
// granularity). Labels are wave-uniform scalar loads. Epilogue unchanged.
__global__ __launch_bounds__(256) void k1_sums(const float* __restrict__ x,
                                               const float* __restrict__ y,
                                               float* __restrict__ ws, int N) {
    __shared__ float lsum[4][TYPE_N][D];
    __shared__ float lcnt[4][TYPE_N];
    const int lane = threadIdx.x & 63;
    const int sub  = threadIdx.x >> 6;
    const int r0   = blockIdx.x * RPB;
    const int rows = (N - r0 < RPB) ? (N - r0) : RPB;
    // this wave's contiguous sub-slab [wbase, wbase + wrows)
    const int wbase = r0 + 32 * sub;
    int wrows = rows - 32 * sub;
    wrows = (wrows < 0) ? 0 : ((wrows > 32) ? 32 : wrows);

    float acc[TYPE_N][4] = {};
    float cnt[TYPE_N] = {};
    const float cw = (lane == 0) ? 1.0f : 0.0f;  // lane0 of each wave counts its rows

    const int ng = wrows >> 2;   // 4 sequential rows per iteration
    for (int i = 0; i < ng; ++i) {
        const int rb = wbase + i * 4;
        // 4 wave-uniform labels (scalarizable loads)
        const int lab0 = argmax5(y + (size_t)(rb + 0) * TYPE_N);
        const int lab1 = argmax5(y + (size_t)(rb + 1) * TYPE_N);
        const int lab2 = argmax5(y + (size_t)(rb + 2) * TYPE_N);
        const int lab3 = argmax5(y + (size_t)(rb + 3) * TYPE_N);
        // 4 independent coalesced 1KB loads at CONSECUTIVE addresses
        const float4 v0 = *reinterpret_cast<const float4*>(
            x + (size_t)(rb + 0) * D + lane * 4);
        const float4 v1 = *reinterpret_cast<const float4*>(
            x + (size_t)(rb + 1) * D + lane * 4);
        const float4 v2 = *reinterpret_cast<const float4*>(
            x + (size_t)(rb + 2) * D + lane * 4);
        const float4 v3 = *reinterpret_cast<const float4*>(
            x + (size_t)(rb + 3) * D + lane * 4);
        #pragma unroll
        for (int c = 0; c < TYPE_N; ++c) {
            const float m0 = (lab0 == c) ? 1.0f : 0.0f;
            acc[c][0] = fmaf(m0, v0.x, acc[c][0]);
            acc[c][1] = fmaf(m0, v0.y, acc[c][1]);
            acc[c][2] = fmaf(m0, v0.z, acc[c][2]);
            acc[c][3] = fmaf(m0, v0.w, acc[c][3]);
            cnt[c]    = fmaf(m0, cw, cnt[c]);
            const float m1 = (lab1 == c) ? 1.0f : 0.0f;
            acc[c][0] = fmaf(m1, v1.x, acc[c][0]);
            acc[c][1] = fmaf(m1, v1.y, acc[c][1]);
            acc[c][2] = fmaf(m1, v1.z, acc[c][2]);
            acc[c][3] = fmaf(m1, v1.w, acc[c][3]);
            cnt[c]    = fmaf(m1, cw, cnt[c]);
            const float m2 = (lab2 == c) ? 1.0f : 0.0f;
            acc[c][0] = fmaf(m2, v2.x, acc[c][0]);
            acc[c][1] = fmaf(m2, v2.y, acc[c][1]);
            acc[c][2] = fmaf(m2, v2.z, acc[c][2]);
            acc[c][3] = fmaf(m2, v2.w, acc[c][3]);
            cnt[c]    = fmaf(m2, cw, cnt[c]);
            const float m3 = (lab3 == c) ? 1.0f : 0.0f;
            acc[c][0] = fmaf(m3, v3.x, acc[c][0]);
            acc[c][1] = fmaf(m3, v3.y, acc[c][1]);
            acc[c][2] = fmaf(m3, v3.z, acc[c][2]);
            acc[c][3] = fmaf(m3, v3.w, acc[c][3]);
            cnt[c]    = fmaf(m3, cw, cnt[c]);
        }
    }
    for (int r = wbase + (ng << 2); r < wbase + wrows; ++r) {  // tail rows (<4)
        const int lab = argmax5(y + (size_t)r * TYPE_N);
        const float4 v = *reinterpret_cast<const float4*>(
            x + (size_t)r * D + lane * 4);
        #pragma unroll
        for (int c = 0; c < TYPE_N; ++c) {
            const float m = (lab == c) ? 1.0f : 0.0f;
            acc[c][0] = fmaf(m, v.x, acc[c][0]);
            acc[c][1] = fmaf(m, v.y, acc[c][1]);
            acc[c][2] = fmaf(m, v.z, acc[c][2]);
            acc[c][3] = fmaf(m, v.w, acc[c][3]);
            cnt[c]    = fmaf(m, cw, cnt[c]);
        }
    }

    #pragma unroll
    for (int c = 0; c < TYPE_N; ++c) {
        *reinterpret_cast<float4*>(&lsum[sub][c][lane * 4]) =
            make_float4(acc[c][0], acc[c][1], acc[c][2], acc[c][3]);
        if (lane == 0) lcnt[sub][c] = cnt[c];
    }
    __syncthreads();
    const int t = threadIdx.x;
    float* sums = ws + (size_t)(blockIdx.x % NCOPY) * (TYPE_N * D);
    #pragma unroll
    for (int c = 0; c < TYPE_N; ++c) {
        float s = lsum[0][c][t] + lsum[1][c][t] + lsum[2][c][t] + lsum[3][c][t];
        atomicAdd(&sums[c * D + t], s);
    }
    if (t < TYPE_N) {
        float s = lcnt[0][t] + lcnt[1][t] + lcnt[2][t] + lcnt[3][t];
        atomicAdd(&ws[OFF_CNTP + (blockIdx.x % NCOPY) * TYPE_N + t], s);
    }
}

// --- K2: reduce copies -> centers (raw + eps-folded) ------------------------
__global__ __launch_bounds__(256) void k2_center(float* __restrict__ ws) {
    const int t = threadIdx.x;  // column 0..255
    float cnts[TYPE_N];
    #pragma unroll
    for (int c = 0; c < TYPE_N; ++c) {
        float s = 0.f;
        #pragma unroll
        for (int p = 0; p < NCOPY; ++p) s += ws[OFF_CNTP + p * TYPE_N + c];
        cnts[c] = s;
    }
    float* center = ws + OFF_CENTER;
    float* cme    = ws + OFF_CME;
    #pragma unroll
    for (int c = 0; c < TYPE_N; ++c) {
        float s = 0.f;
        #pragma unroll
        for (int p = 0; p < NCOPY; ++p) s += ws[p * TYPE_N * D + c * D + t];
        float sc = fmaxf(cnts[c], 1.0f);
        float ctr = (cnts[c] > 0.f) ? s / sc : 0.f;
        center[c * D + t] = ctr;
        cme[c * D + t]    = ctr - EPS;
    }
    if (t < TYPE_N) ws[OFF_CNTF + t] = cnts[t];
}

// --- K3: row-per-thread distances (R11-exact) -------------------------------
__global__ __launch_bounds__(256) void k3_dist(const float* __restrict__ x,
                                               const float* __restrict__ y,
                                               float* __restrict__ ws, int N) {
    __shared__ float lds[4][TYPE_N];
    const int lane = threadIdx.x & 63;
    const int wid  = threadIdx.x >> 6;
    const int r = blockIdx.x * 256 + threadIdx.x;

    int lab = 0;
    float d = 0.f;
    if (r < N) {
        lab = argmax5(y + (size_t)r * TYPE_N);
        const float4* xr = reinterpret_cast<const float4*>(x + (size_t)r * D);
        const float4* cr = reinterpret_cast<const float4*>(ws + OFF_CME + lab * D);
        float ss[4] = {0.f, 0.f, 0.f, 0.f};
        #pragma unroll 8
        for (int i = 0; i < 64; ++i) {
            const float4 a = xr[i];
            const float4 b = cr[i];
            const float t0 = a.x - b.x;
            const float t1 = a.y - b.y;
            const float t2 = a.z - b.z;
            const float t3 = a.w - b.w;
            float s = fmaf(t0, t0, t1 * t1);
            s = fmaf(t2, t2, s);
            s = fmaf(t3, t3, s);
            ss[i & 3] += s;
        }
        d = sqrtf(ss[0] + ss[1] + ss[2] + ss[3]);
    }

    #pragma unroll
    for (int c = 0; c < TYPE_N; ++c) {
        float v = (lab == c) ? d : 0.f;
        #pragma unroll
        for (int off = 32; off > 0; off >>= 1) v += __shfl_xor(v, off);
        if (lane == 0) lds[wid][c] = v;
    }
    __syncthreads();
    if (threadIdx.x < TYPE_N) {
        float s = lds[0][threadIdx.x] + lds[1][threadIdx.x] +
                  lds[2][threadIdx.x] + lds[3][threadIdx.x];
        atomicAdd(&ws[OFF_DSUM + (blockIdx.x % NCOPY) * TYPE_N + threadIdx.x], s);
    }
}

// --- K4: scalar epilogue -----------------------------------------------------
__global__ __launch_bounds__(64) void k4_final(const float* __restrict__ ws,
                                               float* __restrict__ out) {
    const int lane = threadIdx.x;  // 0..63
    const float* center = ws + OFF_CENTER;
    const float* counts = ws + OFF_CNTF;
    const float* dsp    = ws + OFF_DSUM;

    float csum[TYPE_N];
    #pragma unroll
    for (int c = 0; c < TYPE_N; ++c) {
        float s = 0.f;
        #pragma unroll
        for (int k = 0; k < 4; ++k) s += center[c * D + lane * 4 + k];
        #pragma unroll
        for (int off = 32; off > 0; off >>= 1) s += __shfl_xor(s, off);
        csum[c] = s;
    }

    float cnts[TYPE_N], dsum[TYPE_N];
    bool present[TYPE_N];
    float real_n = 0.f;
    #pragma unroll
    for (int c = 0; c < TYPE_N; ++c) {
        cnts[c] = counts[c];
        float s = 0.f;
        #pragma unroll
        for (int p = 0; p < NCOPY; ++p) s += dsp[p * TYPE_N + c];
        dsum[c] = s;
        present[c] = (cnts[c] > 0.f) && (csum[c] != 0.f);
        real_n += present[c] ? 1.f : 0.f;
    }

    float loss_pos = 0.f;
    #pragma unroll
    for (int c = 0; c < TYPE_N; ++c) {
        float pcm = dsum[c] / fmaxf(cnts[c], 1.f);
        loss_pos += present[c] ? pcm : 0.f;
    }
    loss_pos = (real_n > 0.f) ? loss_pos / fmaxf(real_n, 1.f) : 1.0f;

    float pairsum = 0.f;
    #pragma unroll
    for (int i = 0; i < TYPE_N; ++i) {
        #pragma unroll
        for (int j = i + 1; j < TYPE_N; ++j) {
            float s = 0.f;
            #pragma unroll
            for (int k = 0; k < 4; ++k) {
                float dd = center[i * D + lane * 4 + k] - center[j * D + lane * 4 + k] + EPS;
                s += dd * dd;
            }
            #pragma unroll
            for (int off = 32; off > 0; off >>= 1) s += __shfl_xor(s, off);
            float pd = sqrtf(s);
            pairsum += (present[i] && present[j]) ? pd : 0.f;
        }
    }
    float n_pairs = real_n * (real_n - 1.f) * 0.5f;
    float loss_neg = (real_n > 1.f) ? pairsum / fmaxf(n_pairs, 1.f) : 0.f;

    if (lane == 0) out[0] = loss_pos / (loss_neg + loss_pos);
}

extern "C" void kernel_launch(void* const* d_in, const int* in_sizes, int n_in,
                              void* d_out, int out_size, void* d_ws, size_t ws_size,
                              hipStream_t stream) {
    const float* x = (const float*)d_in[0];
    const float* y = (const float*)d_in[1];
    float* out = (float*)d_out;
    float* ws  = (float*)d_ws;
    const int N = in_sizes[0] / D;  // 200000

    (void)hipMemsetAsync(d_ws, 0, (size_t)WS_FLOATS * sizeof(float), stream);

    const int grid1 = (N + RPB - 1) / RPB;   // 1563 blocks, 128 rows each
    k1_sums<<<grid1, 256, 0, stream>>>(x, y, ws, N);
    k2_center<<<1, 256, 0, stream>>>(ws);
    const int grid3 = (N + 255) / 256;       // one row per thread
    k3_dist<<<grid3, 256, 0, stream>>>(x, y, ws, N);
    k4_final<<<1, 64, 0, stream>>>(ws, out);
}